// Round 4
// baseline (525.224 us; speedup 1.0000x reference)
//
#include <hip/hip_runtime.h>

// MultiHeadLinearAttention (B=8,S=4096,IN=1024,H=16,D=64). ALL I/O fp32.
//   k = x@wk + bk ; K = elu(k)+1 ; v = x@wv + bv
//   KV[b,c] = sum_s K*v (elementwise), Ksum[b,c] = sum_s K
//   out[b,s,:] = gelu_tanh((KV_b/Ksum_b)@wo + bo) — s-independent broadcast.
// v6: v5's skeleton (all-gload_lds staging, 8 counted vmem/STAGE, 32x32x16
//   MFMA, 2x16-MFMA phases) with the LDS tile layout TRANSPOSED to
//   [unit(8)][row(256)] x 16B. Frag reads (fixed k-unit, 32 consecutive rows)
//   are 512B contiguous -> bank-conflict-free with NO swizzle (v5's row&7
//   swizzle was structurally 4-way-conflicted at 128B row stride). Staging
//   keeps linear LDS dests (slot = j*512+t); global addrs become per-lane
//   row-strided (lane=row, thread-constant unit).

#define SEQ   4096
#define MROWS 32768
#define KDIM  1024
#define HD    1024
#define TILES 16

typedef __bf16 bf16x8 __attribute__((ext_vector_type(8)));
typedef float floatx4 __attribute__((ext_vector_type(4)));
typedef float floatx16 __attribute__((ext_vector_type(16)));

__device__ __forceinline__ unsigned short f2bf(float f) {
    unsigned int u = __float_as_uint(f);
    u += 0x7fffu + ((u >> 16) & 1u);   // RNE
    return (unsigned short)(u >> 16);
}
__device__ __forceinline__ void cvt8(const float* __restrict__ p, unsigned short* d) {
    const float4 a = *(const float4*)p;
    const float4 b = *(const float4*)(p + 4);
    d[0] = f2bf(a.x); d[1] = f2bf(a.y); d[2] = f2bf(a.z); d[3] = f2bf(a.w);
    d[4] = f2bf(b.x); d[5] = f2bf(b.y); d[6] = f2bf(b.z); d[7] = f2bf(b.w);
}

typedef const __attribute__((address_space(1))) unsigned int* gas_t;
typedef __attribute__((address_space(3))) unsigned int* las_t;
__device__ __forceinline__ void async16(const void* g, void* l) {
    // one global_load_lds_dwordx4: LDS dst = readfirstlane(l) + lane*16
    __builtin_amdgcn_global_load_lds((gas_t)g, (las_t)l, 16, 0, 0);
}

// ---------- Prepass A: x fp32 -> bf16 ----------
__global__ __launch_bounds__(256)
void cvt_x(const float* __restrict__ x, unsigned short* __restrict__ xb)
{
    const size_t p = ((size_t)blockIdx.x * 256 + threadIdx.x) * 8;
    union { uint4 u; unsigned short s[8]; } o;
    cvt8(x + p, o.s);
    *(uint4*)(xb + p) = o.u;
}

// ---------- Prepass B: W[k][n] fp32 -> WT[n][k] bf16 (64x64 tiles) ----------
__global__ __launch_bounds__(256)
void transpose_w(const float* __restrict__ wk, const float* __restrict__ wv,
                 unsigned short* __restrict__ wkT, unsigned short* __restrict__ wvT)
{
    __shared__ alignas(16) unsigned short Ts[64][72];
    const float* W = blockIdx.z ? wv : wk;
    unsigned short* WT = blockIdx.z ? wvT : wkT;
    const int k0 = blockIdx.x * 64, n0 = blockIdx.y * 64;
    const int t = threadIdx.x;
    const int r4 = (t >> 4) * 4, c4 = (t & 15) * 4;
#pragma unroll
    for (int i = 0; i < 4; i++) {
        const float4 f = *(const float4*)(W + (size_t)(k0 + r4 + i) * HD + n0 + c4);
        Ts[c4 + 0][r4 + i] = f2bf(f.x);
        Ts[c4 + 1][r4 + i] = f2bf(f.y);
        Ts[c4 + 2][r4 + i] = f2bf(f.z);
        Ts[c4 + 3][r4 + i] = f2bf(f.w);
    }
    __syncthreads();
    const int rr = t >> 3, cc = (t & 7) * 8;
#pragma unroll
    for (int h = 0; h < 2; h++)
        *(uint4*)(WT + (size_t)(n0 + rr + h * 32) * KDIM + k0 + cc) =
            *(const uint4*)&Ts[rr + h * 32][cc];
}

// ---------- Kernel 1 (fast): 32x32x16 dual-B GEMM, transposed LDS tiles ----
// grid 1024 x 512 thr. BM=256 rows, BN=128 cols for BOTH K and V. BK=64.
// 8 waves as 4m x 2n; wave tile 64m x 64n per matrix; acc = 2x2x2 x f32x16.
// LDS: As[2]/Bs[2] 32 KiB each, layout [unit 0..7][row 0..255] x 16B
// (B rows 0-127 = K, 128-255 = V). Frag read = fixed unit, 32 consecutive
// rows -> contiguous, conflict-free. 8 async16 per STAGE -> vmcnt(8).
__global__ __launch_bounds__(512, 2)
void kv_gemm_fast(const unsigned short* __restrict__ xb,
                  const unsigned short* __restrict__ wkT,
                  const unsigned short* __restrict__ wvT,
                  const float* __restrict__ bk, const float* __restrict__ bv,
                  float2* __restrict__ KVZ)
{
    __shared__ alignas(16) unsigned short As[2][256 * 64];   // 2 x 32 KiB
    __shared__ alignas(16) unsigned short Bs[2][256 * 64];   // 2 x 32 KiB

    const int t = threadIdx.x;

    // T1 bijective XCD decode: 1024 = 8 XCDs x (16 mtiles x 8 ntiles).
    const int id = blockIdx.x;
    const int xcd = id & 7, o = id >> 3;
    const int mtile = xcd * 16 + (o >> 3);   // 0..127
    const int ntile = o & 7;                 // 0..7
    const int m0 = mtile * 256;
    const int n0 = ntile * 128;
    const int b  = m0 >> 12;

    const int w = t >> 6, lane = t & 63;
    const int wm = w >> 1, wn = w & 1;       // 4m x 2n
    const int l32 = lane & 31, half = lane >> 5;

    int arow[2], brow[2];
#pragma unroll
    for (int i = 0; i < 2; i++) {
        arow[i] = wm * 64 + i * 32 + l32;
        brow[i] = wn * 64 + i * 32 + l32;
    }

    // ---- staging geometry: call j stages slot s=j*512+t (16B each);
    // unit = s>>8 = j*2 + (t>>8), row = s&255 = t&255. LDS dest linear in t.
    const int grow = t & 255;                // global tile row
    const int u0   = t >> 8;                 // 0 or 1
    const unsigned short* gAbase = xb + (size_t)(m0 + grow) * KDIM + u0 * 8;
    const unsigned short* gBbase =
        (grow < 128) ? (wkT + (size_t)(n0 + grow) * KDIM + u0 * 8)
                     : (wvT + (size_t)(n0 + grow - 128) * KDIM + u0 * 8);

#define STAGE(c, tk) do {                                                     \
        const int ko_ = (tk) * 64;                                            \
        async16(gAbase + ko_,      &As[c][(0 * 512 + t) * 8]);                \
        async16(gAbase + ko_ + 16, &As[c][(1 * 512 + t) * 8]);                \
        async16(gAbase + ko_ + 32, &As[c][(2 * 512 + t) * 8]);                \
        async16(gAbase + ko_ + 48, &As[c][(3 * 512 + t) * 8]);                \
        async16(gBbase + ko_,      &Bs[c][(0 * 512 + t) * 8]);                \
        async16(gBbase + ko_ + 16, &Bs[c][(1 * 512 + t) * 8]);                \
        async16(gBbase + ko_ + 32, &Bs[c][(2 * 512 + t) * 8]);                \
        async16(gBbase + ko_ + 48, &Bs[c][(3 * 512 + t) * 8]);                \
    } while (0)

    STAGE(0, 0);
    STAGE(1, 1);

    floatx16 accK[2][2], accV[2][2];
#pragma unroll
    for (int i = 0; i < 2; i++)
#pragma unroll
        for (int j = 0; j < 2; j++) {
            accK[i][j] = (floatx16)(0.f);
            accV[i][j] = (floatx16)(0.f);
        }

    // tile0 ready when only tile1's 8 loads remain outstanding
    asm volatile("s_waitcnt vmcnt(8)" ::: "memory");
    __builtin_amdgcn_s_barrier();

    for (int tk = 0; tk < TILES; ++tk) {
        const int c = tk & 1;
        const unsigned short* A = As[c];
        const unsigned short* B = Bs[c];

#pragma unroll
        for (int ph = 0; ph < 2; ++ph) {
            bf16x8 af[2][2], bK[2][2], bV[2][2];
#pragma unroll
            for (int k2 = 0; k2 < 2; ++k2) {
                const int u = ((ph * 2 + k2) << 1) | half;   // k-unit 0..7
#pragma unroll
                for (int mi = 0; mi < 2; ++mi)
                    af[mi][k2] = *(const bf16x8*)&A[u * 2048 + arow[mi] * 8];
#pragma unroll
                for (int ni = 0; ni < 2; ++ni) {
                    bK[ni][k2] = *(const bf16x8*)&B[u * 2048 +  brow[ni]        * 8];
                    bV[ni][k2] = *(const bf16x8*)&B[u * 2048 + (brow[ni] + 128) * 8];
                }
            }
            __builtin_amdgcn_s_barrier();      // cluster waves per phase
            __builtin_amdgcn_s_setprio(1);
#pragma unroll
            for (int k2 = 0; k2 < 2; ++k2)
#pragma unroll
                for (int mi = 0; mi < 2; ++mi)
#pragma unroll
                    for (int ni = 0; ni < 2; ++ni) {
                        accK[mi][ni] = __builtin_amdgcn_mfma_f32_32x32x16_bf16(
                            af[mi][k2], bK[ni][k2], accK[mi][ni], 0, 0, 0);
                        accV[mi][ni] = __builtin_amdgcn_mfma_f32_32x32x16_bf16(
                            af[mi][k2], bV[ni][k2], accV[mi][ni], 0, 0, 0);
                    }
            __builtin_amdgcn_s_setprio(0);
        }

        __builtin_amdgcn_s_barrier();            // all waves done with buf c
        if (tk + 2 < TILES) {
            STAGE(c, tk + 2);
            asm volatile("s_waitcnt vmcnt(8)" ::: "memory"); // tile tk+1 landed
        } else if (tk == TILES - 2) {
            asm volatile("s_waitcnt vmcnt(0)" ::: "memory"); // tile 15 landed
        }
        __builtin_amdgcn_s_barrier();
    }
#undef STAGE

    // Epilogue: 32x32 C/D: col = lane&31; 16 regs + both lane-halves cover
    // the 32 rows of a frag -> sum regs, shfl_xor(32), one atomic per col.
#pragma unroll
    for (int ni = 0; ni < 2; ++ni) {
        const int colw = n0 + wn * 64 + ni * 32 + l32;
        const float bkf = bk[colw];
        const float bvf = bv[colw];
        float pKV = 0.f, pK = 0.f;
#pragma unroll
        for (int mi = 0; mi < 2; ++mi) {
#pragma unroll
            for (int r = 0; r < 16; ++r) {
                const float kv = accK[mi][ni][r] + bkf;
                const float K  = (kv > 0.f) ? (kv + 1.f) : __expf(kv);
                const float vv = accV[mi][ni][r] + bvf;
                pKV += K * vv;
                pK  += K;
            }
        }
        pKV += __shfl_xor(pKV, 32, 64);
        pK  += __shfl_xor(pK, 32, 64);
        if (half == 0) {
            atomicAdd(&KVZ[b * HD + colw].x, pKV);
            atomicAdd(&KVZ[b * HD + colw].y, pK);
        }
    }
}

// ---------- Kernel 1 (fallback, verified): fp32 staging ----------
__global__ __launch_bounds__(256)
void kv_gemm(const float* __restrict__ x,
             const float* __restrict__ wk, const float* __restrict__ bk,
             const float* __restrict__ wv, const float* __restrict__ bv,
             float2* __restrict__ KVZ)
{
    __shared__ alignas(16) unsigned short As [128][40];
    __shared__ alignas(16) unsigned short BsK[128][40];
    __shared__ alignas(16) unsigned short BsV[128][40];

    const int t = threadIdx.x;
    const int n0 = blockIdx.x * 128;
    const int m0 = blockIdx.y * 128;
    const int b  = m0 >> 12;

    const int wave = t >> 6, lane = t & 63;
    const int wm = wave >> 1, wn = wave & 1;
    const int lrow = lane & 15, quad = lane >> 4;

    floatx4 accK[4][4], accV[4][4];
#pragma unroll
    for (int i = 0; i < 4; i++)
#pragma unroll
        for (int j = 0; j < 4; j++) {
            accK[i][j] = (floatx4){0.f, 0.f, 0.f, 0.f};
            accV[i][j] = (floatx4){0.f, 0.f, 0.f, 0.f};
        }

    const int arow0 = t >> 2, akc = (t & 3) * 8;
    const int bk0 = t >> 4, bnc = (t & 15) * 8;

    for (int k0 = 0; k0 < KDIM; k0 += 32) {
        __syncthreads();
        {
            union { uint4 u; unsigned short s[8]; } ua, ub;
            cvt8(x + (size_t)(m0 + arow0) * KDIM + k0 + akc, ua.s);
            cvt8(x + (size_t)(m0 + arow0 + 64) * KDIM + k0 + akc, ub.s);
            *(uint4*)&As[arow0][akc] = ua.u;
            *(uint4*)&As[arow0 + 64][akc] = ub.u;
        }
        {
            unsigned short k0s[8], k1s[8], v0s[8], v1s[8];
            cvt8(wk + (size_t)(k0 + bk0) * HD + n0 + bnc, k0s);
            cvt8(wk + (size_t)(k0 + bk0 + 16) * HD + n0 + bnc, k1s);
            cvt8(wv + (size_t)(k0 + bk0) * HD + n0 + bnc, v0s);
            cvt8(wv + (size_t)(k0 + bk0 + 16) * HD + n0 + bnc, v1s);
#pragma unroll
            for (int j = 0; j < 8; j++) {
                BsK[bnc + j][bk0]      = k0s[j];
                BsK[bnc + j][bk0 + 16] = k1s[j];
                BsV[bnc + j][bk0]      = v0s[j];
                BsV[bnc + j][bk0 + 16] = v1s[j];
            }
        }
        __syncthreads();

        bf16x8 af[4], bfK[4], bfV[4];
#pragma unroll
        for (int mi = 0; mi < 4; mi++)
            af[mi] = *(const bf16x8*)&As[wm * 64 + mi * 16 + lrow][quad * 8];
#pragma unroll
        for (int ni = 0; ni < 4; ni++) {
            bfK[ni] = *(const bf16x8*)&BsK[wn * 64 + ni * 16 + lrow][quad * 8];
            bfV[ni] = *(const bf16x8*)&BsV[wn * 64 + ni * 16 + lrow][quad * 8];
        }
#pragma unroll
        for (int mi = 0; mi < 4; mi++)
#pragma unroll
            for (int ni = 0; ni < 4; ni++) {
                accK[mi][ni] = __builtin_amdgcn_mfma_f32_16x16x32_bf16(
                    af[mi], bfK[ni], accK[mi][ni], 0, 0, 0);
                accV[mi][ni] = __builtin_amdgcn_mfma_f32_16x16x32_bf16(
                    af[mi], bfV[ni], accV[mi][ni], 0, 0, 0);
            }
    }

#pragma unroll
    for (int ni = 0; ni < 4; ni++) {
        const int colw = n0 + wn * 64 + ni * 16 + lrow;
        const float bkf = bk[colw];
        const float bvf = bv[colw];
        float pKV = 0.f, pK = 0.f;
#pragma unroll
        for (int mi = 0; mi < 4; mi++) {
#pragma unroll
            for (int r = 0; r < 4; r++) {
                const float kk = accK[mi][ni][r] + bkf;
                const float K  = (kk > 0.f) ? (kk + 1.f) : __expf(kk);
                const float vv = accV[mi][ni][r] + bvf;
                pKV += K * vv;
                pK  += K;
            }
        }
        pKV += __shfl_xor(pKV, 16, 64);
        pKV += __shfl_xor(pKV, 32, 64);
        pK  += __shfl_xor(pK, 16, 64);
        pK  += __shfl_xor(pK, 32, 64);
        if (quad == 0) {
            atomicAdd(&KVZ[b * HD + colw].x, pKV);
            atomicAdd(&KVZ[b * HD + colw].y, pK);
        }
    }
}

// ---------- Kernel 2 (fused): gelu((KV/Ksum)@wo + bo) broadcast to out -----
// grid (8, 16, 8): block (b, o-chunk of 64, s-chunk of 512).
__global__ __launch_bounds__(256)
void rowgemm_bcast(const float2* __restrict__ KVZ,
                   const float* __restrict__ wo, const float* __restrict__ bo,
                   float* __restrict__ out)
{
    __shared__ float a[1024];
    __shared__ float red[4][64];
    __shared__ float sval[64];
    const int t = threadIdx.x;
    const int b = blockIdx.x;
    const int o0 = blockIdx.y * 64;
    const int s0 = blockIdx.z * 512;

    for (int c = t; c < 1024; c += 256) {
        const float2 z = KVZ[b * HD + c];
        a[c] = z.x / z.y;
    }
    __syncthreads();

    const int cs = t >> 6, oi = t & 63;
    float p = 0.f;
    const int cbeg = cs * 256;
    for (int c = cbeg; c < cbeg + 256; ++c)
        p += a[c] * wo[(size_t)c * HD + o0 + oi];
    red[cs][oi] = p;
    __syncthreads();

    if (t < 64) {
        float v = red[0][t] + red[1][t] + red[2][t] + red[3][t] + bo[o0 + t];
        sval[t] = 0.5f * v *
            (1.f + tanhf(0.7978845608028654f * (v + 0.044715f * v * v * v)));
    }
    __syncthreads();

    const float4 sv4 = *(const float4*)&sval[(t & 15) * 4];
    for (int r = t >> 4; r < 512; r += 16)
        *(float4*)&out[((size_t)(b * SEQ + s0 + r)) * HD + o0 + (t & 15) * 4] = sv4;
}

// ---------- Fallback epilogue kernels ----------
__global__ __launch_bounds__(256)
void rowgemm(const float2* __restrict__ KVZ,
             const float* __restrict__ wo, const float* __restrict__ bo,
             float* __restrict__ rowf)
{
    __shared__ float a[1024];
    __shared__ float red[4][64];
    const int t = threadIdx.x;
    const int b = blockIdx.x;
    const int o0 = blockIdx.y * 64;

    for (int c = t; c < 1024; c += 256) {
        const float2 z = KVZ[b * HD + c];
        a[c] = z.x / z.y;
    }
    __syncthreads();

    const int cs = t >> 6, oi = t & 63;
    float p = 0.f;
    const int cbeg = cs * 256;
    for (int c = cbeg; c < cbeg + 256; ++c)
        p += a[c] * wo[(size_t)c * HD + o0 + oi];
    red[cs][oi] = p;
    __syncthreads();

    if (t < 64) {
        float v = red[0][t] + red[1][t] + red[2][t] + red[3][t] + bo[o0 + t];
        const float g = 0.5f * v *
            (1.f + tanhf(0.7978845608028654f * (v + 0.044715f * v * v * v)));
        rowf[b * HD + o0 + t] = g;
    }
}

__global__ __launch_bounds__(256)
void broadcast_rows(const float* __restrict__ rowf, float* __restrict__ out)
{
    const size_t idx = (size_t)blockIdx.x * 256 + threadIdx.x;
    const size_t p = idx * 4;
    const int row = (int)(p >> 10);
    const int b = row >> 12;
    const int col = (int)(p & 1023);
    *(float4*)(out + p) = *(const float4*)(rowf + b * HD + col);
}

extern "C" void kernel_launch(void* const* d_in, const int* in_sizes, int n_in,
                              void* d_out, int out_size, void* d_ws, size_t ws_size,
                              hipStream_t stream)
{
    const float* x  = (const float*)d_in[0];
    const float* wk = (const float*)d_in[3];
    const float* bk = (const float*)d_in[4];
    const float* wv = (const float*)d_in[5];
    const float* bv = (const float*)d_in[6];
    const float* wo = (const float*)d_in[7];
    const float* bo = (const float*)d_in[8];
    float* out = (float*)d_out;

    const size_t NEED = (size_t)72 * 1024 * 1024;
    if (ws_size >= NEED) {
        unsigned short* xb  = (unsigned short*)d_ws;                       // 64 MiB
        unsigned short* wkT = (unsigned short*)((char*)d_ws + (67u << 20));// 2 MiB
        unsigned short* wvT = (unsigned short*)((char*)d_ws + (69u << 20));// 2 MiB
        float2* KVZ = (float2*)((char*)d_ws + (71u << 20));                // 64 KiB

        hipMemsetAsync(KVZ, 0, 8 * HD * sizeof(float2), stream);
        cvt_x<<<dim3(MROWS * KDIM / 8 / 256), 256, 0, stream>>>(x, xb);
        transpose_w<<<dim3(16, 16, 2), 256, 0, stream>>>(wk, wv, wkT, wvT);
        kv_gemm_fast<<<dim3(1024), 512, 0, stream>>>(xb, wkT, wvT, bk, bv, KVZ);
        rowgemm_bcast<<<dim3(8, 16, 8), 256, 0, stream>>>(KVZ, wo, bo, out);
    } else {
        float2* KVZ = (float2*)d_ws;
        float* rowf = (float*)((char*)d_ws + 65536);
        hipMemsetAsync(KVZ, 0, 8 * HD * sizeof(float2), stream);
        kv_gemm<<<dim3(8, 256), 256, 0, stream>>>(x, wk, bk, wv, bv, KVZ);
        rowgemm<<<dim3(8, 16), 256, 0, stream>>>(KVZ, wo, bo, rowf);
        broadcast_rows<<<dim3((MROWS * HD / 4) / 256), 256, 0, stream>>>(rowf, out);
    }
}

// Round 5
// 408.867 us; speedup vs baseline: 1.2846x; 1.2846x over previous
//
#include <hip/hip_runtime.h>

// MultiHeadLinearAttention (B=8,S=4096,IN=1024,H=16,D=64). ALL I/O fp32.
//   k = x@wk + bk ; K = elu(k)+1 ; v = x@wv + bv
//   KV[b,c] = sum_s K*v (elementwise), Ksum[b,c] = sum_s K
//   out[b,s,:] = gelu_tanh((KV_b/Ksum_b)@wo + bo) — s-independent broadcast.
// v7: back to the verified v3 compute (16x16x32 MFMA, coalesced gload_lds
//   staging, 0-conflict reads) but deep-pipelined: BK=32, FOUR 32-KiB LDS
//   buffer sets (same 128 KiB), prefetch depth 3, ONE barrier per tile
//   (stage(t+3) targets buffer (t-1)&3, already dead for 2 barriers).
//   vmcnt wait has ~3 tile-times of slack vs ~900cyc HBM. Swizzle for the
//   [row][32] tile: u' = u ^ ((row>>1)&3) — 16 rows x 4 quads spread evenly
//   over all 8 (parity,unit) bank groups = conflict-free b128 reads.

#define SEQ   4096
#define MROWS 32768
#define KDIM  1024
#define HD    1024
#define T32   32          // K-tiles of 32

typedef __bf16 bf16x8 __attribute__((ext_vector_type(8)));
typedef float floatx4 __attribute__((ext_vector_type(4)));

__device__ __forceinline__ unsigned short f2bf(float f) {
    unsigned int u = __float_as_uint(f);
    u += 0x7fffu + ((u >> 16) & 1u);   // RNE
    return (unsigned short)(u >> 16);
}
__device__ __forceinline__ void cvt8(const float* __restrict__ p, unsigned short* d) {
    const float4 a = *(const float4*)p;
    const float4 b = *(const float4*)(p + 4);
    d[0] = f2bf(a.x); d[1] = f2bf(a.y); d[2] = f2bf(a.z); d[3] = f2bf(a.w);
    d[4] = f2bf(b.x); d[5] = f2bf(b.y); d[6] = f2bf(b.z); d[7] = f2bf(b.w);
}

typedef const __attribute__((address_space(1))) unsigned int* gas_t;
typedef __attribute__((address_space(3))) unsigned int* las_t;
__device__ __forceinline__ void async16(const void* g, void* l) {
    // one global_load_lds_dwordx4: LDS dst = readfirstlane(l) + lane*16
    __builtin_amdgcn_global_load_lds((gas_t)g, (las_t)l, 16, 0, 0);
}

// ---------- Prepass A: x fp32 -> bf16 ----------
__global__ __launch_bounds__(256)
void cvt_x(const float* __restrict__ x, unsigned short* __restrict__ xb)
{
    const size_t p = ((size_t)blockIdx.x * 256 + threadIdx.x) * 8;
    union { uint4 u; unsigned short s[8]; } o;
    cvt8(x + p, o.s);
    *(uint4*)(xb + p) = o.u;
}

// ---------- Prepass B: W[k][n] fp32 -> WT[n][k] bf16 (64x64 tiles) ----------
__global__ __launch_bounds__(256)
void transpose_w(const float* __restrict__ wk, const float* __restrict__ wv,
                 unsigned short* __restrict__ wkT, unsigned short* __restrict__ wvT)
{
    __shared__ alignas(16) unsigned short Ts[64][72];
    const float* W = blockIdx.z ? wv : wk;
    unsigned short* WT = blockIdx.z ? wvT : wkT;
    const int k0 = blockIdx.x * 64, n0 = blockIdx.y * 64;
    const int t = threadIdx.x;
    const int r4 = (t >> 4) * 4, c4 = (t & 15) * 4;
#pragma unroll
    for (int i = 0; i < 4; i++) {
        const float4 f = *(const float4*)(W + (size_t)(k0 + r4 + i) * HD + n0 + c4);
        Ts[c4 + 0][r4 + i] = f2bf(f.x);
        Ts[c4 + 1][r4 + i] = f2bf(f.y);
        Ts[c4 + 2][r4 + i] = f2bf(f.z);
        Ts[c4 + 3][r4 + i] = f2bf(f.w);
    }
    __syncthreads();
    const int rr = t >> 3, cc = (t & 7) * 8;
#pragma unroll
    for (int h = 0; h < 2; h++)
        *(uint4*)(WT + (size_t)(n0 + rr + h * 32) * KDIM + k0 + cc) =
            *(const uint4*)&Ts[rr + h * 32][cc];
}

// ---------- Kernel 1 (fast): 16x16x32 dual-B GEMM, 4-deep pipeline ----------
// grid 1024 x 512 thr. BM=256 rows, BN=128 cols for BOTH K and V. BK=32.
// 8 waves as 4m x 2n; wave tile 64m x 64n per matrix; acc 4x4x2 x f32x4.
// LDS: As[4]/Bs[4] 16 KiB each = 128 KiB. Layout [row][32] (64B rows),
// swizzle u' = u ^ ((row>>1)&3) on 16B units (pre-swizzled gload source +
// swizzled ds_read, rule #21). 4 async16/STAGE -> counted vmcnt multiples
// of 4. One barrier per tile; prefetch depth 3.
__global__ __launch_bounds__(512, 1)
void kv_gemm_fast(const unsigned short* __restrict__ xb,
                  const unsigned short* __restrict__ wkT,
                  const unsigned short* __restrict__ wvT,
                  const float* __restrict__ bk, const float* __restrict__ bv,
                  float2* __restrict__ KVZ)
{
    __shared__ alignas(16) unsigned short As[4][256 * 32];   // 4 x 16 KiB
    __shared__ alignas(16) unsigned short Bs[4][256 * 32];   // 4 x 16 KiB

    const int t = threadIdx.x;

    // T1 bijective XCD decode: 1024 = 8 XCDs x (16 mtiles x 8 ntiles).
    const int id = blockIdx.x;
    const int xcd = id & 7, o = id >> 3;
    const int mtile = xcd * 16 + (o >> 3);   // 0..127
    const int ntile = o & 7;                 // 0..7
    const int m0 = mtile * 256;
    const int n0 = ntile * 128;
    const int b  = m0 >> 12;

    const int w = t >> 6, lane = t & 63;
    const int wm = w >> 1, wn = w & 1;       // 4m x 2n
    const int lrow = lane & 15, quad = lane >> 4;

    // conflict-free read swizzle: u' = quad ^ ((row>>1)&3); row ≡ lrow mod 16
    // and both 16-row frag offsets and the +128 V offset keep (row>>1)&3.
    const int usw = quad ^ ((lrow >> 1) & 3);

    // ---- staging: call j covers 16B unit g=j*512+t: row=g>>2, u=g&3.
    // Pre-swizzle source unit: u_src = (t&3) ^ ((t>>3)&3)  (row=t>>2).
    const int srow  = t >> 2;                        // 0..127
    const int usrc  = (t & 3) ^ ((t >> 3) & 3);
    const unsigned short* gA0 = xb  + (size_t)(m0 + srow) * KDIM + usrc * 8;
    const unsigned short* gA1 = gA0 + (size_t)128 * KDIM;
    const unsigned short* gBk = wkT + (size_t)(n0 + srow) * KDIM + usrc * 8;
    const unsigned short* gBv = wvT + (size_t)(n0 + srow) * KDIM + usrc * 8;

#define STAGE(c, tk) do {                                                     \
        const int ko_ = (tk) * 32;                                            \
        async16(gA0 + ko_, &As[c][(0 * 512 + t) * 8]);                        \
        async16(gA1 + ko_, &As[c][(1 * 512 + t) * 8]);                        \
        async16(gBk + ko_, &Bs[c][(0 * 512 + t) * 8]);                        \
        async16(gBv + ko_, &Bs[c][(1 * 512 + t) * 8]);                        \
    } while (0)

    STAGE(0, 0);
    STAGE(1, 1);
    STAGE(2, 2);

    floatx4 accK[4][4], accV[4][4];
#pragma unroll
    for (int i = 0; i < 4; i++)
#pragma unroll
        for (int j = 0; j < 4; j++) {
            accK[i][j] = (floatx4){0.f, 0.f, 0.f, 0.f};
            accV[i][j] = (floatx4){0.f, 0.f, 0.f, 0.f};
        }

    asm volatile("s_waitcnt vmcnt(8)" ::: "memory");   // tile 0 landed
    __builtin_amdgcn_s_barrier();

    for (int tk = 0; tk < T32; ++tk) {
        const unsigned short* A = As[tk & 3];
        const unsigned short* B = Bs[tk & 3];

        bf16x8 af[4], bK[4], bV[4];
#pragma unroll
        for (int mi = 0; mi < 4; ++mi)
            af[mi] = *(const bf16x8*)&A[(wm * 64 + mi * 16 + lrow) * 32 + usw * 8];
#pragma unroll
        for (int ni = 0; ni < 4; ++ni) {
            const int br = wn * 64 + ni * 16 + lrow;
            bK[ni] = *(const bf16x8*)&B[ br        * 32 + usw * 8];
            bV[ni] = *(const bf16x8*)&B[(br + 128) * 32 + usw * 8];
        }

        __builtin_amdgcn_s_setprio(1);
#pragma unroll
        for (int mi = 0; mi < 4; ++mi)
#pragma unroll
            for (int ni = 0; ni < 4; ++ni) {
                accK[mi][ni] = __builtin_amdgcn_mfma_f32_16x16x32_bf16(
                    af[mi], bK[ni], accK[mi][ni], 0, 0, 0);
                accV[mi][ni] = __builtin_amdgcn_mfma_f32_16x16x32_bf16(
                    af[mi], bV[ni], accV[mi][ni], 0, 0, 0);
            }
        __builtin_amdgcn_s_setprio(0);

        // boundary: stage tile tk+3 into buffer (tk-1)&3 (dead for 2 barriers)
        // then make sure tile tk+1 has landed, one barrier, go.
        if (tk + 3 < T32) {
            STAGE((tk + 3) & 3, tk + 3);
            asm volatile("s_waitcnt vmcnt(8)" ::: "memory");  // t+2,t+3 in flight
        } else if (tk == T32 - 3) {
            asm volatile("s_waitcnt vmcnt(4)" ::: "memory");  // only t+2 in flight
        } else if (tk == T32 - 2) {
            asm volatile("s_waitcnt vmcnt(0)" ::: "memory");  // last tile landed
        }
        __builtin_amdgcn_s_barrier();
    }
#undef STAGE

    // Epilogue (verified v3): 16x16 C/D col = lane&15, rows = quad*4+r.
    // Sum regs over mi,r; shfl_xor 16+32 across quads; quad==0 atomics.
#pragma unroll
    for (int ni = 0; ni < 4; ++ni) {
        const int colw = n0 + wn * 64 + ni * 16 + lrow;
        const float bkf = bk[colw];
        const float bvf = bv[colw];
        float pKV = 0.f, pK = 0.f;
#pragma unroll
        for (int mi = 0; mi < 4; ++mi) {
#pragma unroll
            for (int r = 0; r < 4; ++r) {
                const float kk = accK[mi][ni][r] + bkf;
                const float K  = (kk > 0.f) ? (kk + 1.f) : __expf(kk);
                const float vv = accV[mi][ni][r] + bvf;
                pKV += K * vv;
                pK  += K;
            }
        }
        pKV += __shfl_xor(pKV, 16, 64);
        pKV += __shfl_xor(pKV, 32, 64);
        pK  += __shfl_xor(pK, 16, 64);
        pK  += __shfl_xor(pK, 32, 64);
        if (quad == 0) {
            atomicAdd(&KVZ[b * HD + colw].x, pKV);
            atomicAdd(&KVZ[b * HD + colw].y, pK);
        }
    }
}

// ---------- Kernel 1 (fallback, verified): fp32 staging ----------
__global__ __launch_bounds__(256)
void kv_gemm(const float* __restrict__ x,
             const float* __restrict__ wk, const float* __restrict__ bk,
             const float* __restrict__ wv, const float* __restrict__ bv,
             float2* __restrict__ KVZ)
{
    __shared__ alignas(16) unsigned short As [128][40];
    __shared__ alignas(16) unsigned short BsK[128][40];
    __shared__ alignas(16) unsigned short BsV[128][40];

    const int t = threadIdx.x;
    const int n0 = blockIdx.x * 128;
    const int m0 = blockIdx.y * 128;
    const int b  = m0 >> 12;

    const int wave = t >> 6, lane = t & 63;
    const int wm = wave >> 1, wn = wave & 1;
    const int lrow = lane & 15, quad = lane >> 4;

    floatx4 accK[4][4], accV[4][4];
#pragma unroll
    for (int i = 0; i < 4; i++)
#pragma unroll
        for (int j = 0; j < 4; j++) {
            accK[i][j] = (floatx4){0.f, 0.f, 0.f, 0.f};
            accV[i][j] = (floatx4){0.f, 0.f, 0.f, 0.f};
        }

    const int arow0 = t >> 2, akc = (t & 3) * 8;
    const int bk0 = t >> 4, bnc = (t & 15) * 8;

    for (int k0 = 0; k0 < KDIM; k0 += 32) {
        __syncthreads();
        {
            union { uint4 u; unsigned short s[8]; } ua, ub;
            cvt8(x + (size_t)(m0 + arow0) * KDIM + k0 + akc, ua.s);
            cvt8(x + (size_t)(m0 + arow0 + 64) * KDIM + k0 + akc, ub.s);
            *(uint4*)&As[arow0][akc] = ua.u;
            *(uint4*)&As[arow0 + 64][akc] = ub.u;
        }
        {
            unsigned short k0s[8], k1s[8], v0s[8], v1s[8];
            cvt8(wk + (size_t)(k0 + bk0) * HD + n0 + bnc, k0s);
            cvt8(wk + (size_t)(k0 + bk0 + 16) * HD + n0 + bnc, k1s);
            cvt8(wv + (size_t)(k0 + bk0) * HD + n0 + bnc, v0s);
            cvt8(wv + (size_t)(k0 + bk0 + 16) * HD + n0 + bnc, v1s);
#pragma unroll
            for (int j = 0; j < 8; j++) {
                BsK[bnc + j][bk0]      = k0s[j];
                BsK[bnc + j][bk0 + 16] = k1s[j];
                BsV[bnc + j][bk0]      = v0s[j];
                BsV[bnc + j][bk0 + 16] = v1s[j];
            }
        }
        __syncthreads();

        bf16x8 af[4], bfK[4], bfV[4];
#pragma unroll
        for (int mi = 0; mi < 4; mi++)
            af[mi] = *(const bf16x8*)&As[wm * 64 + mi * 16 + lrow][quad * 8];
#pragma unroll
        for (int ni = 0; ni < 4; ni++) {
            bfK[ni] = *(const bf16x8*)&BsK[wn * 64 + ni * 16 + lrow][quad * 8];
            bfV[ni] = *(const bf16x8*)&BsV[wn * 64 + ni * 16 + lrow][quad * 8];
        }
#pragma unroll
        for (int mi = 0; mi < 4; mi++)
#pragma unroll
            for (int ni = 0; ni < 4; ni++) {
                accK[mi][ni] = __builtin_amdgcn_mfma_f32_16x16x32_bf16(
                    af[mi], bfK[ni], accK[mi][ni], 0, 0, 0);
                accV[mi][ni] = __builtin_amdgcn_mfma_f32_16x16x32_bf16(
                    af[mi], bfV[ni], accV[mi][ni], 0, 0, 0);
            }
    }

#pragma unroll
    for (int ni = 0; ni < 4; ni++) {
        const int colw = n0 + wn * 64 + ni * 16 + lrow;
        const float bkf = bk[colw];
        const float bvf = bv[colw];
        float pKV = 0.f, pK = 0.f;
#pragma unroll
        for (int mi = 0; mi < 4; mi++) {
#pragma unroll
            for (int r = 0; r < 4; r++) {
                const float kk = accK[mi][ni][r] + bkf;
                const float K  = (kk > 0.f) ? (kk + 1.f) : __expf(kk);
                const float vv = accV[mi][ni][r] + bvf;
                pKV += K * vv;
                pK  += K;
            }
        }
        pKV += __shfl_xor(pKV, 16, 64);
        pKV += __shfl_xor(pKV, 32, 64);
        pK  += __shfl_xor(pK, 16, 64);
        pK  += __shfl_xor(pK, 32, 64);
        if (quad == 0) {
            atomicAdd(&KVZ[b * HD + colw].x, pKV);
            atomicAdd(&KVZ[b * HD + colw].y, pK);
        }
    }
}

// ---------- Kernel 2 (fused): gelu((KV/Ksum)@wo + bo) broadcast to out -----
// grid (8, 16, 8): block (b, o-chunk of 64, s-chunk of 512).
__global__ __launch_bounds__(256)
void rowgemm_bcast(const float2* __restrict__ KVZ,
                   const float* __restrict__ wo, const float* __restrict__ bo,
                   float* __restrict__ out)
{
    __shared__ float a[1024];
    __shared__ float red[4][64];
    __shared__ float sval[64];
    const int t = threadIdx.x;
    const int b = blockIdx.x;
    const int o0 = blockIdx.y * 64;
    const int s0 = blockIdx.z * 512;

    for (int c = t; c < 1024; c += 256) {
        const float2 z = KVZ[b * HD + c];
        a[c] = z.x / z.y;
    }
    __syncthreads();

    const int cs = t >> 6, oi = t & 63;
    float p = 0.f;
    const int cbeg = cs * 256;
    for (int c = cbeg; c < cbeg + 256; ++c)
        p += a[c] * wo[(size_t)c * HD + o0 + oi];
    red[cs][oi] = p;
    __syncthreads();

    if (t < 64) {
        float v = red[0][t] + red[1][t] + red[2][t] + red[3][t] + bo[o0 + t];
        sval[t] = 0.5f * v *
            (1.f + tanhf(0.7978845608028654f * (v + 0.044715f * v * v * v)));
    }
    __syncthreads();

    const float4 sv4 = *(const float4*)&sval[(t & 15) * 4];
    for (int r = t >> 4; r < 512; r += 16)
        *(float4*)&out[((size_t)(b * SEQ + s0 + r)) * HD + o0 + (t & 15) * 4] = sv4;
}

// ---------- Fallback epilogue kernels ----------
__global__ __launch_bounds__(256)
void rowgemm(const float2* __restrict__ KVZ,
             const float* __restrict__ wo, const float* __restrict__ bo,
             float* __restrict__ rowf)
{
    __shared__ float a[1024];
    __shared__ float red[4][64];
    const int t = threadIdx.x;
    const int b = blockIdx.x;
    const int o0 = blockIdx.y * 64;

    for (int c = t; c < 1024; c += 256) {
        const float2 z = KVZ[b * HD + c];
        a[c] = z.x / z.y;
    }
    __syncthreads();

    const int cs = t >> 6, oi = t & 63;
    float p = 0.f;
    const int cbeg = cs * 256;
    for (int c = cbeg; c < cbeg + 256; ++c)
        p += a[c] * wo[(size_t)c * HD + o0 + oi];
    red[cs][oi] = p;
    __syncthreads();

    if (t < 64) {
        float v = red[0][t] + red[1][t] + red[2][t] + red[3][t] + bo[o0 + t];
        const float g = 0.5f * v *
            (1.f + tanhf(0.7978845608028654f * (v + 0.044715f * v * v * v)));
        rowf[b * HD + o0 + t] = g;
    }
}

__global__ __launch_bounds__(256)
void broadcast_rows(const float* __restrict__ rowf, float* __restrict__ out)
{
    const size_t idx = (size_t)blockIdx.x * 256 + threadIdx.x;
    const size_t p = idx * 4;
    const int row = (int)(p >> 10);
    const int b = row >> 12;
    const int col = (int)(p & 1023);
    *(float4*)(out + p) = *(const float4*)(rowf + b * HD + col);
}

extern "C" void kernel_launch(void* const* d_in, const int* in_sizes, int n_in,
                              void* d_out, int out_size, void* d_ws, size_t ws_size,
                              hipStream_t stream)
{
    const float* x  = (const float*)d_in[0];
    const float* wk = (const float*)d_in[3];
    const float* bk = (const float*)d_in[4];
    const float* wv = (const float*)d_in[5];
    const float* bv = (const float*)d_in[6];
    const float* wo = (const float*)d_in[7];
    const float* bo = (const float*)d_in[8];
    float* out = (float*)d_out;

    const size_t NEED = (size_t)72 * 1024 * 1024;
    if (ws_size >= NEED) {
        unsigned short* xb  = (unsigned short*)d_ws;                       // 64 MiB
        unsigned short* wkT = (unsigned short*)((char*)d_ws + (67u << 20));// 2 MiB
        unsigned short* wvT = (unsigned short*)((char*)d_ws + (69u << 20));// 2 MiB
        float2* KVZ = (float2*)((char*)d_ws + (71u << 20));                // 64 KiB

        hipMemsetAsync(KVZ, 0, 8 * HD * sizeof(float2), stream);
        cvt_x<<<dim3(MROWS * KDIM / 8 / 256), 256, 0, stream>>>(x, xb);
        transpose_w<<<dim3(16, 16, 2), 256, 0, stream>>>(wk, wv, wkT, wvT);
        kv_gemm_fast<<<dim3(1024), 512, 0, stream>>>(xb, wkT, wvT, bk, bv, KVZ);
        rowgemm_bcast<<<dim3(8, 16, 8), 256, 0, stream>>>(KVZ, wo, bo, out);
    } else {
        float2* KVZ = (float2*)d_ws;
        float* rowf = (float*)((char*)d_ws + 65536);
        hipMemsetAsync(KVZ, 0, 8 * HD * sizeof(float2), stream);
        kv_gemm<<<dim3(8, 256), 256, 0, stream>>>(x, wk, bk, wv, bv, KVZ);
        rowgemm<<<dim3(8, 16), 256, 0, stream>>>(KVZ, wo, bo, rowf);
        broadcast_rows<<<dim3((MROWS * HD / 4) / 256), 256, 0, stream>>>(rowf, out);
    }
}

// Round 6
// 405.049 us; speedup vs baseline: 1.2967x; 1.0094x over previous
//
#include <hip/hip_runtime.h>

// MultiHeadLinearAttention (B=8,S=4096,IN=1024,H=16,D=64). ALL I/O fp32.
//   k = x@wk + bk ; K = elu(k)+1 ; v = x@wv + bv
//   KV[b,c] = sum_s K*v (elementwise), Ksum[b,c] = sum_s K
//   out[b,s,:] = gelu_tanh((KV_b/Ksum_b)@wo + bo) — s-independent broadcast.
// v8 = v7 + intra-wave fragment double-buffering: per tile, ds_read the NEXT
//   tile's fragments (into the alternate named frag set) before issuing the
//   current tile's 32 MFMAs — LDS pipe (~1156 cyc/tile/CU) overlaps matrix
//   pipe (~1242 cyc) instead of serializing. 4-unrolled loop + peeled tail so
//   every buffer index / frag-set choice is compile-time (rule #20). Counted
//   vmcnt waits are spill-robust: 8 counted stage ops always separate the
//   needed tile from the wait, so extra vmem ops only tighten the wait.

#define SEQ   4096
#define MROWS 32768
#define KDIM  1024
#define HD    1024
#define T32   32          // K-tiles of 32

typedef __bf16 bf16x8 __attribute__((ext_vector_type(8)));
typedef float floatx4 __attribute__((ext_vector_type(4)));

__device__ __forceinline__ unsigned short f2bf(float f) {
    unsigned int u = __float_as_uint(f);
    u += 0x7fffu + ((u >> 16) & 1u);   // RNE
    return (unsigned short)(u >> 16);
}
__device__ __forceinline__ void cvt8(const float* __restrict__ p, unsigned short* d) {
    const float4 a = *(const float4*)p;
    const float4 b = *(const float4*)(p + 4);
    d[0] = f2bf(a.x); d[1] = f2bf(a.y); d[2] = f2bf(a.z); d[3] = f2bf(a.w);
    d[4] = f2bf(b.x); d[5] = f2bf(b.y); d[6] = f2bf(b.z); d[7] = f2bf(b.w);
}

typedef const __attribute__((address_space(1))) unsigned int* gas_t;
typedef __attribute__((address_space(3))) unsigned int* las_t;
__device__ __forceinline__ void async16(const void* g, void* l) {
    // one global_load_lds_dwordx4: LDS dst = readfirstlane(l) + lane*16
    __builtin_amdgcn_global_load_lds((gas_t)g, (las_t)l, 16, 0, 0);
}

// ---------- Prepass A: x fp32 -> bf16 ----------
__global__ __launch_bounds__(256)
void cvt_x(const float* __restrict__ x, unsigned short* __restrict__ xb)
{
    const size_t p = ((size_t)blockIdx.x * 256 + threadIdx.x) * 8;
    union { uint4 u; unsigned short s[8]; } o;
    cvt8(x + p, o.s);
    *(uint4*)(xb + p) = o.u;
}

// ---------- Prepass B: W[k][n] fp32 -> WT[n][k] bf16 (64x64 tiles) ----------
__global__ __launch_bounds__(256)
void transpose_w(const float* __restrict__ wk, const float* __restrict__ wv,
                 unsigned short* __restrict__ wkT, unsigned short* __restrict__ wvT)
{
    __shared__ alignas(16) unsigned short Ts[64][72];
    const float* W = blockIdx.z ? wv : wk;
    unsigned short* WT = blockIdx.z ? wvT : wkT;
    const int k0 = blockIdx.x * 64, n0 = blockIdx.y * 64;
    const int t = threadIdx.x;
    const int r4 = (t >> 4) * 4, c4 = (t & 15) * 4;
#pragma unroll
    for (int i = 0; i < 4; i++) {
        const float4 f = *(const float4*)(W + (size_t)(k0 + r4 + i) * HD + n0 + c4);
        Ts[c4 + 0][r4 + i] = f2bf(f.x);
        Ts[c4 + 1][r4 + i] = f2bf(f.y);
        Ts[c4 + 2][r4 + i] = f2bf(f.z);
        Ts[c4 + 3][r4 + i] = f2bf(f.w);
    }
    __syncthreads();
    const int rr = t >> 3, cc = (t & 7) * 8;
#pragma unroll
    for (int h = 0; h < 2; h++)
        *(uint4*)(WT + (size_t)(n0 + rr + h * 32) * KDIM + k0 + cc) =
            *(const uint4*)&Ts[rr + h * 32][cc];
}

// ---------- Kernel 1 (fast): 16x16x32 dual-B GEMM, frag-dbuf pipeline ------
// grid 1024 x 512 thr. BM=256, BN=128 each for K and V. BK=32. 8 waves 4m x 2n.
// LDS: As[4]/Bs[4] 16 KiB each = 128 KiB, layout [row][32], swizzle
// u' = u ^ ((row>>1)&3) (pre-swizzled gload source + swizzled read).
// Per tile: STAGE(t+3) -> vmcnt(8) -> barrier -> fragload(t+1, alt set)
// -> 32 MFMA(t, cur set). One barrier/tile; prefetch depth 3.
__global__ __launch_bounds__(512, 2)
void kv_gemm_fast(const unsigned short* __restrict__ xb,
                  const unsigned short* __restrict__ wkT,
                  const unsigned short* __restrict__ wvT,
                  const float* __restrict__ bk, const float* __restrict__ bv,
                  float2* __restrict__ KVZ)
{
    __shared__ alignas(16) unsigned short As[4][256 * 32];   // 4 x 16 KiB
    __shared__ alignas(16) unsigned short Bs[4][256 * 32];   // 4 x 16 KiB

    const int t = threadIdx.x;

    // T1 bijective XCD decode: 1024 = 8 XCDs x (16 mtiles x 8 ntiles).
    const int id = blockIdx.x;
    const int xcd = id & 7, o = id >> 3;
    const int mtile = xcd * 16 + (o >> 3);   // 0..127
    const int ntile = o & 7;                 // 0..7
    const int m0 = mtile * 256;
    const int n0 = ntile * 128;
    const int b  = m0 >> 12;

    const int w = t >> 6, lane = t & 63;
    const int wm = w >> 1, wn = w & 1;       // 4m x 2n
    const int lrow = lane & 15, quad = lane >> 4;

    // conflict-free read swizzle (v7-verified): u' = quad ^ ((row>>1)&3)
    const int usw = quad ^ ((lrow >> 1) & 3);

    // staging (v7-verified): call j covers 16B unit g=j*512+t: row=g>>2,u=g&3
    const int srow  = t >> 2;                        // 0..127
    const int usrc  = (t & 3) ^ ((t >> 3) & 3);
    const unsigned short* gA0 = xb  + (size_t)(m0 + srow) * KDIM + usrc * 8;
    const unsigned short* gA1 = gA0 + (size_t)128 * KDIM;
    const unsigned short* gBk = wkT + (size_t)(n0 + srow) * KDIM + usrc * 8;
    const unsigned short* gBv = wvT + (size_t)(n0 + srow) * KDIM + usrc * 8;

#define STAGE(c, tk) do {                                                     \
        const int ko_ = (tk) * 32;                                            \
        async16(gA0 + ko_, &As[c][(0 * 512 + t) * 8]);                        \
        async16(gA1 + ko_, &As[c][(1 * 512 + t) * 8]);                        \
        async16(gBk + ko_, &Bs[c][(0 * 512 + t) * 8]);                        \
        async16(gBv + ko_, &Bs[c][(1 * 512 + t) * 8]);                        \
    } while (0)

    // two named fragment sets (static indexing only — rule #20)
    bf16x8 afA[4], bKA[4], bVA[4];
    bf16x8 afB[4], bKB[4], bVB[4];

#define LOADSET(af_, bK_, bV_, c) do {                                        \
        _Pragma("unroll")                                                     \
        for (int mi = 0; mi < 4; ++mi)                                        \
            af_[mi] = *(const bf16x8*)&As[c][(wm * 64 + mi * 16 + lrow) * 32 + usw * 8]; \
        _Pragma("unroll")                                                     \
        for (int ni = 0; ni < 4; ++ni) {                                      \
            const int br_ = wn * 64 + ni * 16 + lrow;                         \
            bK_[ni] = *(const bf16x8*)&Bs[c][ br_        * 32 + usw * 8];     \
            bV_[ni] = *(const bf16x8*)&Bs[c][(br_ + 128) * 32 + usw * 8];     \
        }                                                                     \
    } while (0)

#define MFMASET(af_, bK_, bV_) do {                                           \
        __builtin_amdgcn_s_setprio(1);                                        \
        _Pragma("unroll")                                                     \
        for (int mi = 0; mi < 4; ++mi)                                        \
            _Pragma("unroll")                                                 \
            for (int ni = 0; ni < 4; ++ni) {                                  \
                accK[mi][ni] = __builtin_amdgcn_mfma_f32_16x16x32_bf16(       \
                    af_[mi], bK_[ni], accK[mi][ni], 0, 0, 0);                 \
                accV[mi][ni] = __builtin_amdgcn_mfma_f32_16x16x32_bf16(       \
                    af_[mi], bV_[ni], accV[mi][ni], 0, 0, 0);                 \
            }                                                                 \
        __builtin_amdgcn_s_setprio(0);                                        \
    } while (0)

#define WAIT8 asm volatile("s_waitcnt vmcnt(8)" ::: "memory")
#define BAR   __builtin_amdgcn_s_barrier()

    floatx4 accK[4][4], accV[4][4];
#pragma unroll
    for (int i = 0; i < 4; i++)
#pragma unroll
        for (int j = 0; j < 4; j++) {
            accK[i][j] = (floatx4){0.f, 0.f, 0.f, 0.f};
            accV[i][j] = (floatx4){0.f, 0.f, 0.f, 0.f};
        }

    // prologue: tiles 0..2 in flight; tile0 landed; preload its frags (set A)
    STAGE(0, 0);
    STAGE(1, 1);
    STAGE(2, 2);
    WAIT8;                       // 12 outstanding -> 8: tile0 landed
    BAR;
    LOADSET(afA, bKA, bVA, 0);

    // main loop: tiles 0..27, 4-unrolled so buf indices & frag sets are static
    for (int it = 0; it < 7; ++it) {
        const int tk = it * 4;
        STAGE(3, tk + 3); WAIT8; BAR; LOADSET(afB, bKB, bVB, 1); MFMASET(afA, bKA, bVA);
        STAGE(0, tk + 4); WAIT8; BAR; LOADSET(afA, bKA, bVA, 2); MFMASET(afB, bKB, bVB);
        STAGE(1, tk + 5); WAIT8; BAR; LOADSET(afB, bKB, bVB, 3); MFMASET(afA, bKA, bVA);
        STAGE(2, tk + 6); WAIT8; BAR; LOADSET(afA, bKA, bVA, 0); MFMASET(afB, bKB, bVB);
    }

    // peeled tail: tiles 28..31
    STAGE(3, 31); WAIT8; BAR;                       // tile29 landed
    LOADSET(afB, bKB, bVB, 1); MFMASET(afA, bKA, bVA);          // tile 28
    asm volatile("s_waitcnt vmcnt(4)" ::: "memory"); BAR;       // tile30 landed
    LOADSET(afA, bKA, bVA, 2); MFMASET(afB, bKB, bVB);          // tile 29
    asm volatile("s_waitcnt vmcnt(0)" ::: "memory"); BAR;       // tile31 landed
    LOADSET(afB, bKB, bVB, 3); MFMASET(afA, bKA, bVA);          // tile 30
    MFMASET(afB, bKB, bVB);                                     // tile 31

#undef STAGE
#undef LOADSET
#undef MFMASET
#undef WAIT8
#undef BAR

    // Epilogue (verified): 16x16 C/D col = lane&15, rows = quad*4+r.
#pragma unroll
    for (int ni = 0; ni < 4; ++ni) {
        const int colw = n0 + wn * 64 + ni * 16 + lrow;
        const float bkf = bk[colw];
        const float bvf = bv[colw];
        float pKV = 0.f, pK = 0.f;
#pragma unroll
        for (int mi = 0; mi < 4; ++mi) {
#pragma unroll
            for (int r = 0; r < 4; ++r) {
                const float kk = accK[mi][ni][r] + bkf;
                const float K  = (kk > 0.f) ? (kk + 1.f) : __expf(kk);
                const float vv = accV[mi][ni][r] + bvf;
                pKV += K * vv;
                pK  += K;
            }
        }
        pKV += __shfl_xor(pKV, 16, 64);
        pKV += __shfl_xor(pKV, 32, 64);
        pK  += __shfl_xor(pK, 16, 64);
        pK  += __shfl_xor(pK, 32, 64);
        if (quad == 0) {
            atomicAdd(&KVZ[b * HD + colw].x, pKV);
            atomicAdd(&KVZ[b * HD + colw].y, pK);
        }
    }
}

// ---------- Kernel 1 (fallback, verified): fp32 staging ----------
__global__ __launch_bounds__(256)
void kv_gemm(const float* __restrict__ x,
             const float* __restrict__ wk, const float* __restrict__ bk,
             const float* __restrict__ wv, const float* __restrict__ bv,
             float2* __restrict__ KVZ)
{
    __shared__ alignas(16) unsigned short As [128][40];
    __shared__ alignas(16) unsigned short BsK[128][40];
    __shared__ alignas(16) unsigned short BsV[128][40];

    const int t = threadIdx.x;
    const int n0 = blockIdx.x * 128;
    const int m0 = blockIdx.y * 128;
    const int b  = m0 >> 12;

    const int wave = t >> 6, lane = t & 63;
    const int wm = wave >> 1, wn = wave & 1;
    const int lrow = lane & 15, quad = lane >> 4;

    floatx4 accK[4][4], accV[4][4];
#pragma unroll
    for (int i = 0; i < 4; i++)
#pragma unroll
        for (int j = 0; j < 4; j++) {
            accK[i][j] = (floatx4){0.f, 0.f, 0.f, 0.f};
            accV[i][j] = (floatx4){0.f, 0.f, 0.f, 0.f};
        }

    const int arow0 = t >> 2, akc = (t & 3) * 8;
    const int bk0 = t >> 4, bnc = (t & 15) * 8;

    for (int k0 = 0; k0 < KDIM; k0 += 32) {
        __syncthreads();
        {
            union { uint4 u; unsigned short s[8]; } ua, ub;
            cvt8(x + (size_t)(m0 + arow0) * KDIM + k0 + akc, ua.s);
            cvt8(x + (size_t)(m0 + arow0 + 64) * KDIM + k0 + akc, ub.s);
            *(uint4*)&As[arow0][akc] = ua.u;
            *(uint4*)&As[arow0 + 64][akc] = ub.u;
        }
        {
            unsigned short k0s[8], k1s[8], v0s[8], v1s[8];
            cvt8(wk + (size_t)(k0 + bk0) * HD + n0 + bnc, k0s);
            cvt8(wk + (size_t)(k0 + bk0 + 16) * HD + n0 + bnc, k1s);
            cvt8(wv + (size_t)(k0 + bk0) * HD + n0 + bnc, v0s);
            cvt8(wv + (size_t)(k0 + bk0 + 16) * HD + n0 + bnc, v1s);
#pragma unroll
            for (int j = 0; j < 8; j++) {
                BsK[bnc + j][bk0]      = k0s[j];
                BsK[bnc + j][bk0 + 16] = k1s[j];
                BsV[bnc + j][bk0]      = v0s[j];
                BsV[bnc + j][bk0 + 16] = v1s[j];
            }
        }
        __syncthreads();

        bf16x8 af[4], bfK[4], bfV[4];
#pragma unroll
        for (int mi = 0; mi < 4; mi++)
            af[mi] = *(const bf16x8*)&As[wm * 64 + mi * 16 + lrow][quad * 8];
#pragma unroll
        for (int ni = 0; ni < 4; ni++) {
            bfK[ni] = *(const bf16x8*)&BsK[wn * 64 + ni * 16 + lrow][quad * 8];
            bfV[ni] = *(const bf16x8*)&BsV[wn * 64 + ni * 16 + lrow][quad * 8];
        }
#pragma unroll
        for (int mi = 0; mi < 4; mi++)
#pragma unroll
            for (int ni = 0; ni < 4; ni++) {
                accK[mi][ni] = __builtin_amdgcn_mfma_f32_16x16x32_bf16(
                    af[mi], bfK[ni], accK[mi][ni], 0, 0, 0);
                accV[mi][ni] = __builtin_amdgcn_mfma_f32_16x16x32_bf16(
                    af[mi], bfV[ni], accV[mi][ni], 0, 0, 0);
            }
    }

#pragma unroll
    for (int ni = 0; ni < 4; ni++) {
        const int colw = n0 + wn * 64 + ni * 16 + lrow;
        const float bkf = bk[colw];
        const float bvf = bv[colw];
        float pKV = 0.f, pK = 0.f;
#pragma unroll
        for (int mi = 0; mi < 4; mi++) {
#pragma unroll
            for (int r = 0; r < 4; r++) {
                const float kk = accK[mi][ni][r] + bkf;
                const float K  = (kk > 0.f) ? (kk + 1.f) : __expf(kk);
                const float vv = accV[mi][ni][r] + bvf;
                pKV += K * vv;
                pK  += K;
            }
        }
        pKV += __shfl_xor(pKV, 16, 64);
        pKV += __shfl_xor(pKV, 32, 64);
        pK  += __shfl_xor(pK, 16, 64);
        pK  += __shfl_xor(pK, 32, 64);
        if (quad == 0) {
            atomicAdd(&KVZ[b * HD + colw].x, pKV);
            atomicAdd(&KVZ[b * HD + colw].y, pK);
        }
    }
}

// ---------- Kernel 2 (fused): gelu((KV/Ksum)@wo + bo) broadcast to out -----
__global__ __launch_bounds__(256)
void rowgemm_bcast(const float2* __restrict__ KVZ,
                   const float* __restrict__ wo, const float* __restrict__ bo,
                   float* __restrict__ out)
{
    __shared__ float a[1024];
    __shared__ float red[4][64];
    __shared__ float sval[64];
    const int t = threadIdx.x;
    const int b = blockIdx.x;
    const int o0 = blockIdx.y * 64;
    const int s0 = blockIdx.z * 512;

    for (int c = t; c < 1024; c += 256) {
        const float2 z = KVZ[b * HD + c];
        a[c] = z.x / z.y;
    }
    __syncthreads();

    const int cs = t >> 6, oi = t & 63;
    float p = 0.f;
    const int cbeg = cs * 256;
    for (int c = cbeg; c < cbeg + 256; ++c)
        p += a[c] * wo[(size_t)c * HD + o0 + oi];
    red[cs][oi] = p;
    __syncthreads();

    if (t < 64) {
        float v = red[0][t] + red[1][t] + red[2][t] + red[3][t] + bo[o0 + t];
        sval[t] = 0.5f * v *
            (1.f + tanhf(0.7978845608028654f * (v + 0.044715f * v * v * v)));
    }
    __syncthreads();

    const float4 sv4 = *(const float4*)&sval[(t & 15) * 4];
    for (int r = t >> 4; r < 512; r += 16)
        *(float4*)&out[((size_t)(b * SEQ + s0 + r)) * HD + o0 + (t & 15) * 4] = sv4;
}

// ---------- Fallback epilogue kernels ----------
__global__ __launch_bounds__(256)
void rowgemm(const float2* __restrict__ KVZ,
             const float* __restrict__ wo, const float* __restrict__ bo,
             float* __restrict__ rowf)
{
    __shared__ float a[1024];
    __shared__ float red[4][64];
    const int t = threadIdx.x;
    const int b = blockIdx.x;
    const int o0 = blockIdx.y * 64;

    for (int c = t; c < 1024; c += 256) {
        const float2 z = KVZ[b * HD + c];
        a[c] = z.x / z.y;
    }
    __syncthreads();

    const int cs = t >> 6, oi = t & 63;
    float p = 0.f;
    const int cbeg = cs * 256;
    for (int c = cbeg; c < cbeg + 256; ++c)
        p += a[c] * wo[(size_t)c * HD + o0 + oi];
    red[cs][oi] = p;
    __syncthreads();

    if (t < 64) {
        float v = red[0][t] + red[1][t] + red[2][t] + red[3][t] + bo[o0 + t];
        const float g = 0.5f * v *
            (1.f + tanhf(0.7978845608028654f * (v + 0.044715f * v * v * v)));
        rowf[b * HD + o0 + t] = g;
    }
}

__global__ __launch_bounds__(256)
void broadcast_rows(const float* __restrict__ rowf, float* __restrict__ out)
{
    const size_t idx = (size_t)blockIdx.x * 256 + threadIdx.x;
    const size_t p = idx * 4;
    const int row = (int)(p >> 10);
    const int b = row >> 12;
    const int col = (int)(p & 1023);
    *(float4*)(out + p) = *(const float4*)(rowf + b * HD + col);
}

extern "C" void kernel_launch(void* const* d_in, const int* in_sizes, int n_in,
                              void* d_out, int out_size, void* d_ws, size_t ws_size,
                              hipStream_t stream)
{
    const float* x  = (const float*)d_in[0];
    const float* wk = (const float*)d_in[3];
    const float* bk = (const float*)d_in[4];
    const float* wv = (const float*)d_in[5];
    const float* bv = (const float*)d_in[6];
    const float* wo = (const float*)d_in[7];
    const float* bo = (const float*)d_in[8];
    float* out = (float*)d_out;

    const size_t NEED = (size_t)72 * 1024 * 1024;
    if (ws_size >= NEED) {
        unsigned short* xb  = (unsigned short*)d_ws;                       // 64 MiB
        unsigned short* wkT = (unsigned short*)((char*)d_ws + (67u << 20));// 2 MiB
        unsigned short* wvT = (unsigned short*)((char*)d_ws + (69u << 20));// 2 MiB
        float2* KVZ = (float2*)((char*)d_ws + (71u << 20));                // 64 KiB

        hipMemsetAsync(KVZ, 0, 8 * HD * sizeof(float2), stream);
        cvt_x<<<dim3(MROWS * KDIM / 8 / 256), 256, 0, stream>>>(x, xb);
        transpose_w<<<dim3(16, 16, 2), 256, 0, stream>>>(wk, wv, wkT, wvT);
        kv_gemm_fast<<<dim3(1024), 512, 0, stream>>>(xb, wkT, wvT, bk, bv, KVZ);
        rowgemm_bcast<<<dim3(8, 16, 8), 256, 0, stream>>>(KVZ, wo, bo, out);
    } else {
        float2* KVZ = (float2*)d_ws;
        float* rowf = (float*)((char*)d_ws + 65536);
        hipMemsetAsync(KVZ, 0, 8 * HD * sizeof(float2), stream);
        kv_gemm<<<dim3(8, 256), 256, 0, stream>>>(x, wk, bk, wv, bv, KVZ);
        rowgemm<<<dim3(8, 16), 256, 0, stream>>>(KVZ, wo, bo, rowf);
        broadcast_rows<<<dim3((MROWS * HD / 4) / 256), 256, 0, stream>>>(rowf, out);
    }
}

// Round 7
// 401.032 us; speedup vs baseline: 1.3097x; 1.0100x over previous
//
#include <hip/hip_runtime.h>

// MultiHeadLinearAttention (B=8,S=4096,IN=1024,H=16,D=64). ALL I/O fp32.
//   k = x@wk + bk ; K = elu(k)+1 ; v = x@wv + bv
//   KV[b,c] = sum_s K*v (elementwise), Ksum[b,c] = sum_s K
//   out[b,s,:] = gelu_tanh((KV_b/Ksum_b)@wo + bo) — s-independent broadcast.
// v9 = v7 (verified: 4x16KiB buffer sets, depth-3 counted vmcnt, swizzle
//   u'=u^((row>>1)&3), 0 conflicts) with the inner loop split into m201-style
//   phases: per tile, {read af+bK; stage A-half; BAR; 16 K-MFMA; BAR} then
//   {read bV; stage B-half; wait; BAR; 16 V-MFMA; BAR}. Finish-skew across
//   8 waves lets LDS and MFMA pipes serve different waves concurrently
//   instead of CU-wide burst alternation. v8's frag-dbuf (spilled) reverted.
//   cvt_x + transpose_w merged into one prep launch.

#define SEQ   4096
#define MROWS 32768
#define KDIM  1024
#define HD    1024
#define T32   32          // K-tiles of 32

typedef __bf16 bf16x8 __attribute__((ext_vector_type(8)));
typedef float floatx4 __attribute__((ext_vector_type(4)));

__device__ __forceinline__ unsigned short f2bf(float f) {
    unsigned int u = __float_as_uint(f);
    u += 0x7fffu + ((u >> 16) & 1u);   // RNE
    return (unsigned short)(u >> 16);
}
__device__ __forceinline__ void cvt8(const float* __restrict__ p, unsigned short* d) {
    const float4 a = *(const float4*)p;
    const float4 b = *(const float4*)(p + 4);
    d[0] = f2bf(a.x); d[1] = f2bf(a.y); d[2] = f2bf(a.z); d[3] = f2bf(a.w);
    d[4] = f2bf(b.x); d[5] = f2bf(b.y); d[6] = f2bf(b.z); d[7] = f2bf(b.w);
}

typedef const __attribute__((address_space(1))) unsigned int* gas_t;
typedef __attribute__((address_space(3))) unsigned int* las_t;
__device__ __forceinline__ void async16(const void* g, void* l) {
    // one global_load_lds_dwordx4: LDS dst = readfirstlane(l) + lane*16
    __builtin_amdgcn_global_load_lds((gas_t)g, (las_t)l, 16, 0, 0);
}

// ---------- Prepass (merged): cvt_x (blocks 0..16383) + transpose_w --------
__global__ __launch_bounds__(256)
void prep(const float* __restrict__ x, unsigned short* __restrict__ xb,
          const float* __restrict__ wk, const float* __restrict__ wv,
          unsigned short* __restrict__ wkT, unsigned short* __restrict__ wvT)
{
    __shared__ alignas(16) unsigned short Ts[64][72];
    const int t = threadIdx.x;
    if (blockIdx.x < 16384) {
        const size_t p = ((size_t)blockIdx.x * 256 + t) * 8;
        union { uint4 u; unsigned short s[8]; } o;
        cvt8(x + p, o.s);
        *(uint4*)(xb + p) = o.u;
        return;
    }
    const int bid = blockIdx.x - 16384;          // 0..511
    const float* W = (bid >> 8) ? wv : wk;
    unsigned short* WT = (bid >> 8) ? wvT : wkT;
    const int k0 = (bid & 15) * 64, n0 = ((bid >> 4) & 15) * 64;
    const int r4 = (t >> 4) * 4, c4 = (t & 15) * 4;
#pragma unroll
    for (int i = 0; i < 4; i++) {
        const float4 f = *(const float4*)(W + (size_t)(k0 + r4 + i) * HD + n0 + c4);
        Ts[c4 + 0][r4 + i] = f2bf(f.x);
        Ts[c4 + 1][r4 + i] = f2bf(f.y);
        Ts[c4 + 2][r4 + i] = f2bf(f.z);
        Ts[c4 + 3][r4 + i] = f2bf(f.w);
    }
    __syncthreads();
    const int rr = t >> 3, cc = (t & 7) * 8;
#pragma unroll
    for (int h = 0; h < 2; h++)
        *(uint4*)(WT + (size_t)(n0 + rr + h * 32) * KDIM + k0 + cc) =
            *(const uint4*)&Ts[rr + h * 32][cc];
}

// ---------- Kernel 1 (fast): 16x16x32 dual-B GEMM, phased pipeline ---------
// grid 1024 x 512 thr. BM=256, BN=128 each for K and V. BK=32. 8 waves 4m x 2n.
// LDS: As[4]/Bs[4] 16 KiB each = 128 KiB, layout [row][32], swizzle
// u' = u ^ ((row>>1)&3). 4 async16/tile (2 per phase). Depth-3 prefetch,
// counted vmcnt(8) steady state (v7-verified). Two phases per tile.
__global__ __launch_bounds__(512, 1)
void kv_gemm_fast(const unsigned short* __restrict__ xb,
                  const unsigned short* __restrict__ wkT,
                  const unsigned short* __restrict__ wvT,
                  const float* __restrict__ bk, const float* __restrict__ bv,
                  float2* __restrict__ KVZ)
{
    __shared__ alignas(16) unsigned short As[4][256 * 32];   // 4 x 16 KiB
    __shared__ alignas(16) unsigned short Bs[4][256 * 32];   // 4 x 16 KiB

    const int t = threadIdx.x;

    // T1 bijective XCD decode: 1024 = 8 XCDs x (16 mtiles x 8 ntiles).
    const int id = blockIdx.x;
    const int xcd = id & 7, o = id >> 3;
    const int mtile = xcd * 16 + (o >> 3);   // 0..127
    const int ntile = o & 7;                 // 0..7
    const int m0 = mtile * 256;
    const int n0 = ntile * 128;
    const int b  = m0 >> 12;

    const int w = t >> 6, lane = t & 63;
    const int wm = w >> 1, wn = w & 1;       // 4m x 2n
    const int lrow = lane & 15, quad = lane >> 4;

    // conflict-free read swizzle (v7-verified): u' = quad ^ ((row>>1)&3)
    const int usw = quad ^ ((lrow >> 1) & 3);

    // staging (v7-verified): call j covers 16B unit g=j*512+t: row=g>>2,u=g&3
    const int srow  = t >> 2;                        // 0..127
    const int usrc  = (t & 3) ^ ((t >> 3) & 3);
    const unsigned short* gA0 = xb  + (size_t)(m0 + srow) * KDIM + usrc * 8;
    const unsigned short* gA1 = gA0 + (size_t)128 * KDIM;
    const unsigned short* gBk = wkT + (size_t)(n0 + srow) * KDIM + usrc * 8;
    const unsigned short* gBv = wvT + (size_t)(n0 + srow) * KDIM + usrc * 8;

#define STAGE_A(c, tk) do {                                                   \
        const int ko_ = (tk) * 32;                                            \
        async16(gA0 + ko_, &As[c][(0 * 512 + t) * 8]);                        \
        async16(gA1 + ko_, &As[c][(1 * 512 + t) * 8]);                        \
    } while (0)
#define STAGE_B(c, tk) do {                                                   \
        const int ko_ = (tk) * 32;                                            \
        async16(gBk + ko_, &Bs[c][(0 * 512 + t) * 8]);                        \
        async16(gBv + ko_, &Bs[c][(1 * 512 + t) * 8]);                        \
    } while (0)
#define BAR   __builtin_amdgcn_s_barrier()
#define SCHED __builtin_amdgcn_sched_barrier(0)

    // prologue: tiles 0..2 in flight (12 ops); tile0 landed at vmcnt<=8
    STAGE_A(0, 0); STAGE_B(0, 0);
    STAGE_A(1, 1); STAGE_B(1, 1);
    STAGE_A(2, 2); STAGE_B(2, 2);

    floatx4 accK[4][4], accV[4][4];
#pragma unroll
    for (int i = 0; i < 4; i++)
#pragma unroll
        for (int j = 0; j < 4; j++) {
            accK[i][j] = (floatx4){0.f, 0.f, 0.f, 0.f};
            accV[i][j] = (floatx4){0.f, 0.f, 0.f, 0.f};
        }

    asm volatile("s_waitcnt vmcnt(8)" ::: "memory");
    BAR;

    for (int tk = 0; tk < T32; ++tk) {
        const int c = tk & 3;
        const unsigned short* A = As[c];
        const unsigned short* B = Bs[c];
        const int nx = (tk + 3) & 3;

        // ---- phase K: read af+bK, issue A-half of stage(t+3), 16 K-MFMAs --
        bf16x8 af[4], bK[4];
#pragma unroll
        for (int mi = 0; mi < 4; ++mi)
            af[mi] = *(const bf16x8*)&A[(wm * 64 + mi * 16 + lrow) * 32 + usw * 8];
#pragma unroll
        for (int ni = 0; ni < 4; ++ni)
            bK[ni] = *(const bf16x8*)&B[(wn * 64 + ni * 16 + lrow) * 32 + usw * 8];
        if (tk + 3 < T32) STAGE_A(nx, tk + 3);
        BAR; SCHED;
        __builtin_amdgcn_s_setprio(1);
#pragma unroll
        for (int mi = 0; mi < 4; ++mi)
#pragma unroll
            for (int ni = 0; ni < 4; ++ni)
                accK[mi][ni] = __builtin_amdgcn_mfma_f32_16x16x32_bf16(
                    af[mi], bK[ni], accK[mi][ni], 0, 0, 0);
        __builtin_amdgcn_s_setprio(0);
        SCHED; BAR;

        // ---- phase V: read bV, issue B-half, boundary wait, 16 V-MFMAs ----
        bf16x8 bV[4];
#pragma unroll
        for (int ni = 0; ni < 4; ++ni)
            bV[ni] = *(const bf16x8*)&B[(128 + wn * 64 + ni * 16 + lrow) * 32 + usw * 8];
        if (tk + 3 < T32) {
            STAGE_B(nx, tk + 3);
            asm volatile("s_waitcnt vmcnt(8)" ::: "memory");  // t+1 landed
        } else if (tk == T32 - 3) {
            asm volatile("s_waitcnt vmcnt(4)" ::: "memory");  // t+1 landed
        } else if (tk == T32 - 2) {
            asm volatile("s_waitcnt vmcnt(0)" ::: "memory");  // tile 31 landed
        }
        BAR; SCHED;
        __builtin_amdgcn_s_setprio(1);
#pragma unroll
        for (int mi = 0; mi < 4; ++mi)
#pragma unroll
            for (int ni = 0; ni < 4; ++ni)
                accV[mi][ni] = __builtin_amdgcn_mfma_f32_16x16x32_bf16(
                    af[mi], bV[ni], accV[mi][ni], 0, 0, 0);
        __builtin_amdgcn_s_setprio(0);
        SCHED; BAR;
    }
#undef STAGE_A
#undef STAGE_B
#undef BAR
#undef SCHED

    // Epilogue (verified): 16x16 C/D col = lane&15, rows = quad*4+r.
#pragma unroll
    for (int ni = 0; ni < 4; ++ni) {
        const int colw = n0 + wn * 64 + ni * 16 + lrow;
        const float bkf = bk[colw];
        const float bvf = bv[colw];
        float pKV = 0.f, pK = 0.f;
#pragma unroll
        for (int mi = 0; mi < 4; ++mi) {
#pragma unroll
            for (int r = 0; r < 4; ++r) {
                const float kk = accK[mi][ni][r] + bkf;
                const float K  = (kk > 0.f) ? (kk + 1.f) : __expf(kk);
                const float vv = accV[mi][ni][r] + bvf;
                pKV += K * vv;
                pK  += K;
            }
        }
        pKV += __shfl_xor(pKV, 16, 64);
        pKV += __shfl_xor(pKV, 32, 64);
        pK  += __shfl_xor(pK, 16, 64);
        pK  += __shfl_xor(pK, 32, 64);
        if (quad == 0) {
            atomicAdd(&KVZ[b * HD + colw].x, pKV);
            atomicAdd(&KVZ[b * HD + colw].y, pK);
        }
    }
}

// ---------- Kernel 1 (fallback, verified): fp32 staging ----------
__global__ __launch_bounds__(256)
void kv_gemm(const float* __restrict__ x,
             const float* __restrict__ wk, const float* __restrict__ bk,
             const float* __restrict__ wv, const float* __restrict__ bv,
             float2* __restrict__ KVZ)
{
    __shared__ alignas(16) unsigned short As [128][40];
    __shared__ alignas(16) unsigned short BsK[128][40];
    __shared__ alignas(16) unsigned short BsV[128][40];

    const int t = threadIdx.x;
    const int n0 = blockIdx.x * 128;
    const int m0 = blockIdx.y * 128;
    const int b  = m0 >> 12;

    const int wave = t >> 6, lane = t & 63;
    const int wm = wave >> 1, wn = wave & 1;
    const int lrow = lane & 15, quad = lane >> 4;

    floatx4 accK[4][4], accV[4][4];
#pragma unroll
    for (int i = 0; i < 4; i++)
#pragma unroll
        for (int j = 0; j < 4; j++) {
            accK[i][j] = (floatx4){0.f, 0.f, 0.f, 0.f};
            accV[i][j] = (floatx4){0.f, 0.f, 0.f, 0.f};
        }

    const int arow0 = t >> 2, akc = (t & 3) * 8;
    const int bk0 = t >> 4, bnc = (t & 15) * 8;

    for (int k0 = 0; k0 < KDIM; k0 += 32) {
        __syncthreads();
        {
            union { uint4 u; unsigned short s[8]; } ua, ub;
            cvt8(x + (size_t)(m0 + arow0) * KDIM + k0 + akc, ua.s);
            cvt8(x + (size_t)(m0 + arow0 + 64) * KDIM + k0 + akc, ub.s);
            *(uint4*)&As[arow0][akc] = ua.u;
            *(uint4*)&As[arow0 + 64][akc] = ub.u;
        }
        {
            unsigned short k0s[8], k1s[8], v0s[8], v1s[8];
            cvt8(wk + (size_t)(k0 + bk0) * HD + n0 + bnc, k0s);
            cvt8(wk + (size_t)(k0 + bk0 + 16) * HD + n0 + bnc, k1s);
            cvt8(wv + (size_t)(k0 + bk0) * HD + n0 + bnc, v0s);
            cvt8(wv + (size_t)(k0 + bk0 + 16) * HD + n0 + bnc, v1s);
#pragma unroll
            for (int j = 0; j < 8; j++) {
                BsK[bnc + j][bk0]      = k0s[j];
                BsK[bnc + j][bk0 + 16] = k1s[j];
                BsV[bnc + j][bk0]      = v0s[j];
                BsV[bnc + j][bk0 + 16] = v1s[j];
            }
        }
        __syncthreads();

        bf16x8 af[4], bfK[4], bfV[4];
#pragma unroll
        for (int mi = 0; mi < 4; mi++)
            af[mi] = *(const bf16x8*)&As[wm * 64 + mi * 16 + lrow][quad * 8];
#pragma unroll
        for (int ni = 0; ni < 4; ni++) {
            bfK[ni] = *(const bf16x8*)&BsK[wn * 64 + ni * 16 + lrow][quad * 8];
            bfV[ni] = *(const bf16x8*)&BsV[wn * 64 + ni * 16 + lrow][quad * 8];
        }
#pragma unroll
        for (int mi = 0; mi < 4; mi++)
#pragma unroll
            for (int ni = 0; ni < 4; ni++) {
                accK[mi][ni] = __builtin_amdgcn_mfma_f32_16x16x32_bf16(
                    af[mi], bfK[ni], accK[mi][ni], 0, 0, 0);
                accV[mi][ni] = __builtin_amdgcn_mfma_f32_16x16x32_bf16(
                    af[mi], bfV[ni], accV[mi][ni], 0, 0, 0);
            }
    }

#pragma unroll
    for (int ni = 0; ni < 4; ni++) {
        const int colw = n0 + wn * 64 + ni * 16 + lrow;
        const float bkf = bk[colw];
        const float bvf = bv[colw];
        float pKV = 0.f, pK = 0.f;
#pragma unroll
        for (int mi = 0; mi < 4; mi++) {
#pragma unroll
            for (int r = 0; r < 4; r++) {
                const float kk = accK[mi][ni][r] + bkf;
                const float K  = (kk > 0.f) ? (kk + 1.f) : __expf(kk);
                const float vv = accV[mi][ni][r] + bvf;
                pKV += K * vv;
                pK  += K;
            }
        }
        pKV += __shfl_xor(pKV, 16, 64);
        pKV += __shfl_xor(pKV, 32, 64);
        pK  += __shfl_xor(pK, 16, 64);
        pK  += __shfl_xor(pK, 32, 64);
        if (quad == 0) {
            atomicAdd(&KVZ[b * HD + colw].x, pKV);
            atomicAdd(&KVZ[b * HD + colw].y, pK);
        }
    }
}

// ---------- Kernel 2 (fused): gelu((KV/Ksum)@wo + bo) broadcast to out -----
__global__ __launch_bounds__(256)
void rowgemm_bcast(const float2* __restrict__ KVZ,
                   const float* __restrict__ wo, const float* __restrict__ bo,
                   float* __restrict__ out)
{
    __shared__ float a[1024];
    __shared__ float red[4][64];
    __shared__ float sval[64];
    const int t = threadIdx.x;
    const int b = blockIdx.x;
    const int o0 = blockIdx.y * 64;
    const int s0 = blockIdx.z * 512;

    for (int c = t; c < 1024; c += 256) {
        const float2 z = KVZ[b * HD + c];
        a[c] = z.x / z.y;
    }
    __syncthreads();

    const int cs = t >> 6, oi = t & 63;
    float p = 0.f;
    const int cbeg = cs * 256;
    for (int c = cbeg; c < cbeg + 256; ++c)
        p += a[c] * wo[(size_t)c * HD + o0 + oi];
    red[cs][oi] = p;
    __syncthreads();

    if (t < 64) {
        float v = red[0][t] + red[1][t] + red[2][t] + red[3][t] + bo[o0 + t];
        sval[t] = 0.5f * v *
            (1.f + tanhf(0.7978845608028654f * (v + 0.044715f * v * v * v)));
    }
    __syncthreads();

    const float4 sv4 = *(const float4*)&sval[(t & 15) * 4];
    for (int r = t >> 4; r < 512; r += 16)
        *(float4*)&out[((size_t)(b * SEQ + s0 + r)) * HD + o0 + (t & 15) * 4] = sv4;
}

// ---------- Fallback epilogue kernels ----------
__global__ __launch_bounds__(256)
void rowgemm(const float2* __restrict__ KVZ,
             const float* __restrict__ wo, const float* __restrict__ bo,
             float* __restrict__ rowf)
{
    __shared__ float a[1024];
    __shared__ float red[4][64];
    const int t = threadIdx.x;
    const int b = blockIdx.x;
    const int o0 = blockIdx.y * 64;

    for (int c = t; c < 1024; c += 256) {
        const float2 z = KVZ[b * HD + c];
        a[c] = z.x / z.y;
    }
    __syncthreads();

    const int cs = t >> 6, oi = t & 63;
    float p = 0.f;
    const int cbeg = cs * 256;
    for (int c = cbeg; c < cbeg + 256; ++c)
        p += a[c] * wo[(size_t)c * HD + o0 + oi];
    red[cs][oi] = p;
    __syncthreads();

    if (t < 64) {
        float v = red[0][t] + red[1][t] + red[2][t] + red[3][t] + bo[o0 + t];
        const float g = 0.5f * v *
            (1.f + tanhf(0.7978845608028654f * (v + 0.044715f * v * v * v)));
        rowf[b * HD + o0 + t] = g;
    }
}

__global__ __launch_bounds__(256)
void broadcast_rows(const float* __restrict__ rowf, float* __restrict__ out)
{
    const size_t idx = (size_t)blockIdx.x * 256 + threadIdx.x;
    const size_t p = idx * 4;
    const int row = (int)(p >> 10);
    const int b = row >> 12;
    const int col = (int)(p & 1023);
    *(float4*)(out + p) = *(const float4*)(rowf + b * HD + col);
}

extern "C" void kernel_launch(void* const* d_in, const int* in_sizes, int n_in,
                              void* d_out, int out_size, void* d_ws, size_t ws_size,
                              hipStream_t stream)
{
    const float* x  = (const float*)d_in[0];
    const float* wk = (const float*)d_in[3];
    const float* bk = (const float*)d_in[4];
    const float* wv = (const float*)d_in[5];
    const float* bv = (const float*)d_in[6];
    const float* wo = (const float*)d_in[7];
    const float* bo = (const float*)d_in[8];
    float* out = (float*)d_out;

    const size_t NEED = (size_t)72 * 1024 * 1024;
    if (ws_size >= NEED) {
        unsigned short* xb  = (unsigned short*)d_ws;                       // 64 MiB
        unsigned short* wkT = (unsigned short*)((char*)d_ws + (67u << 20));// 2 MiB
        unsigned short* wvT = (unsigned short*)((char*)d_ws + (69u << 20));// 2 MiB
        float2* KVZ = (float2*)((char*)d_ws + (71u << 20));                // 64 KiB

        hipMemsetAsync(KVZ, 0, 8 * HD * sizeof(float2), stream);
        prep<<<dim3(16384 + 512), 256, 0, stream>>>(x, xb, wk, wv, wkT, wvT);
        kv_gemm_fast<<<dim3(1024), 512, 0, stream>>>(xb, wkT, wvT, bk, bv, KVZ);
        rowgemm_bcast<<<dim3(8, 16, 8), 256, 0, stream>>>(KVZ, wo, bo, out);
    } else {
        float2* KVZ = (float2*)d_ws;
        float* rowf = (float*)((char*)d_ws + 65536);
        hipMemsetAsync(KVZ, 0, 8 * HD * sizeof(float2), stream);
        kv_gemm<<<dim3(8, 256), 256, 0, stream>>>(x, wk, bk, wv, bv, KVZ);
        rowgemm<<<dim3(8, 16), 256, 0, stream>>>(KVZ, wo, bo, rowf);
        broadcast_rows<<<dim3((MROWS * HD / 4) / 256), 256, 0, stream>>>(rowf, out);
    }
}